// Round 4
// baseline (898.512 us; speedup 1.0000x reference)
//
#include <hip/hip_runtime.h>

// ParabolicPool2D, vertical-first fused form — MEASUREMENT PROBE (REP=4).
// Rounds 1 and 3 (structurally different kernels) gave identical totals (705 vs 711 us);
// pp never appears in the top-5 dispatch list, so its true duration is unresolved between
// ~330us (headroom exists) and ~150us (roofline; harness fills + hidden period-5 dispatches
// dominate). This version repeats the whole body REP=4 times with an opaque zero offset on
// the input pointer (defeats cross-rep load CSE / store sinking), making the pp dispatch
// ~0.5-1.3ms => guaranteed top-1 in the counter table WITH its hbm_gbps / FETCH_SIZE /
// VALUBusy / Occupancy. Output written 4x with identical values -> still correct.
//
// out[b,c,i,j] = max_{u,v} f[b,c,2i+u-3,2j+v-3] + hu[u] + hu[v],  hu[k] = -(k-3)^2/(4t)
// Pass A: v[i][x] = max_u f[2(i0+i)+u-3][x] + hu[u]  (clamped loads, hu masked at y-edges)
// Pass B: out[i][j] = max_u v[i][2j+u-3] + hu[u]     (x-pad cols are -inf)

#define H 256
#define W 256
#define HO 128
#define WO 128
#define TH 16               // output rows per block (strip)
#define VPAD 4              // -inf pad columns each side of v rows
#define VSTRIDE 276         // floats per v row; (276%32)=20 -> b128 accesses bank-balanced
#define REP 4               // measurement repeats (revert to 1 after probe)

__device__ __forceinline__ float4 f4max(float4 a, float4 b) {
    return make_float4(fmaxf(a.x, b.x), fmaxf(a.y, b.y), fmaxf(a.z, b.z), fmaxf(a.w, b.w));
}
__device__ __forceinline__ float4 f4adds(float4 a, float s) {
    return make_float4(a.x + s, a.y + s, a.z + s, a.w + s);
}

__global__ __launch_bounds__(512, 6)
void pp_kernel(const float* __restrict__ f, const float* __restrict__ tptr,
               float* __restrict__ out) {
    __shared__ __align__(16) float v_[TH * VSTRIDE];   // 17664 B

    const int tid = threadIdx.x;
    const int bid = blockIdx.x;
    // 16384 blocks, 8 XCDs, 2048/XCD: bijective swizzle; consecutive lids on one XCD are
    // consecutive strips of the same plane -> y-halo rows hit that XCD's L2.
    const int lid   = (bid & 7) * 2048 + (bid >> 3);
    const int plane = lid >> 3;          // b*128 + c
    const int strip = lid & 7;
    const int i0    = strip * TH;

    const float tv  = tptr[0];
    const float inv = 1.0f / (4.0f * tv);
    const float h0 = -9.0f * inv, h1 = -4.0f * inv, h2 = -1.0f * inv;  // h3 = 0
    const float NEG = -__builtin_inff();

    const float* __restrict__ fplane = f + (size_t)plane * (H * W);

    // x-pad columns: v cols [-4,-1] and [256,259] = -inf (raw float idx 0..3 and 260..263).
    // Written once; Pass A never touches these columns. First Pass-B read is after the
    // Pass-A barrier, which also covers this write.
    if (tid < 32) {
        const int r   = tid & 15;
        const int off = (tid < 16) ? 0 : (VPAD + W);
        *(float4*)(&v_[r * VSTRIDE + off]) = make_float4(NEG, NEG, NEG, NEG);
    }

#pragma unroll 1
    for (int rep = 0; rep < REP; ++rep) {
        // Opaque zero: compiler cannot prove fp == fplane across reps, so global loads are
        // re-issued every rep and stores (whose values depend on the loads) cannot be sunk.
        size_t zoff = 0;
        asm volatile("" : "+s"(zoff));
        const float* __restrict__ fp = fplane + zoff;

        // ---- Pass A: (x4 column group) x (pair of output rows), one item per thread ----
        {
            const int x4    = (tid & 63) * 4;        // float col 0..252 (full row, f4-aligned)
            const int ipair = tid >> 6;              // 0..7 (wave-uniform)
            const int ib    = 2 * ipair;             // tile-local out rows ib, ib+1
            const int gy0   = 2 * (i0 + ib) - 3;     // first of 9 input rows (wave-uniform)

            float4 r[9];
#pragma unroll
            for (int k = 0; k < 9; ++k) {
                const int cy = min(max(gy0 + k, 0), H - 1);   // clamped: always-valid address
                r[k] = *(const float4*)(fp + cy * W + x4);    // wave: contiguous 1KB, coalesced
            }

            float4 vA, vB;
            if (gy0 >= 0 && gy0 + 8 <= H - 1) {
                // interior fast path (wave-uniform branch), symmetric kernel
                vA = f4max(f4max(f4adds(f4max(r[0], r[6]), h0),
                                 f4adds(f4max(r[1], r[5]), h1)),
                           f4max(f4adds(f4max(r[2], r[4]), h2), r[3]));
                vB = f4max(f4max(f4adds(f4max(r[2], r[8]), h0),
                                 f4adds(f4max(r[3], r[7]), h1)),
                           f4max(f4adds(f4max(r[4], r[6]), h2), r[5]));
            } else {
                const float hu[7] = {h0, h1, h2, 0.0f, h2, h1, h0};
                float4 a = make_float4(NEG, NEG, NEG, NEG);
                float4 b = make_float4(NEG, NEG, NEG, NEG);
#pragma unroll
                for (int u = 0; u < 7; ++u) {
                    const int gyA = gy0 + u;
                    const int gyB = gy0 + 2 + u;
                    const float hA = (gyA >= 0 && gyA < H) ? hu[u] : NEG;
                    const float hB = (gyB >= 0 && gyB < H) ? hu[u] : NEG;
                    a = f4max(a, f4adds(r[u], hA));
                    b = f4max(b, f4adds(r[u + 2], hB));
                }
                vA = a; vB = b;
            }

            *(float4*)(&v_[(ib)     * VSTRIDE + VPAD + x4]) = vA;
            *(float4*)(&v_[(ib + 1) * VSTRIDE + VPAD + x4]) = vB;
        }
        __syncthreads();

        // ---- Pass B: horizontal max-plus from LDS, 4 outputs per thread ----
        {
            const int i  = tid >> 5;                 // 0..15 (out row, tile-local)
            const int jg = tid & 31;                 // 0..31 -> out cols 4jg..4jg+3
            const int c0 = 4 * jg;
            const float* p = &v_[i * VSTRIDE + 2 * c0];   // raw idx 8jg, f4-aligned
            const float4 a = *(const float4*)(p);
            const float4 b = *(const float4*)(p + 4);
            const float4 c = *(const float4*)(p + 8);
            const float4 d = *(const float4*)(p + 12);
            const float s[16] = {a.x, a.y, a.z, a.w, b.x, b.y, b.z, b.w,
                                 c.x, c.y, c.z, c.w, d.x, d.y, d.z, d.w};
            float4 o;
            float* op = (float*)&o;
#pragma unroll
            for (int dd = 0; dd < 4; ++dd) {
                // out col j = c0+dd needs raw s-window [2dd+1, 2dd+7]
                const float m0 = fmaxf(s[2 * dd + 1], s[2 * dd + 7]) + h0;
                const float m1 = fmaxf(s[2 * dd + 2], s[2 * dd + 6]) + h1;
                const float m2 = fmaxf(s[2 * dd + 3], s[2 * dd + 5]) + h2;
                op[dd] = fmaxf(fmaxf(m0, m1), fmaxf(m2, s[2 * dd + 4]));
            }
            float* __restrict__ orow = out + (size_t)plane * (HO * WO) + (size_t)(i0 + i) * WO;
            *(float4*)(orow + c0) = o;
        }
        __syncthreads();   // protect v_ before next rep's Pass A overwrites it
    }
}

extern "C" void kernel_launch(void* const* d_in, const int* in_sizes, int n_in,
                              void* d_out, int out_size, void* d_ws, size_t ws_size,
                              hipStream_t stream) {
    const float* f = (const float*)d_in[0];
    const float* t = (const float*)d_in[1];
    float* out = (float*)d_out;
    // 2048 planes x 8 row-strips, 512 threads (one balanced Pass-A item per thread)
    pp_kernel<<<dim3(2048 * 8), dim3(512), 0, stream>>>(f, t, out);
}

// Round 5
// 718.256 us; speedup vs baseline: 1.2510x; 1.2510x over previous
//
#include <hip/hip_runtime.h>

// ParabolicPool2D, vertical-first fused, in-block 2-strip software pipeline.
// Probe (REP=4) decomposition: fixed harness floor ~528us; single-shot kernel ~182us vs
// ~115-120us traffic roofline. Gap = un-overlapped HBM time while blocks sit in barrier /
// Pass-B (LDS) phases. Fix: each block processes TWO consecutive 16-row strips; strip-1's
// 9 global loads are issued (into registers) BEFORE strip-0's Pass B, so HBM fetch overlaps
// the LDS/VALU phase deterministically. Paired strips also share 5 halo rows (L1/L2 hit).
//
// out[b,c,i,j] = max_{u,v} f[b,c,2i+u-3,2j+v-3] + hu[u] + hu[v],  hu[k] = -(k-3)^2/(4t)
// Pass A: v[i][x] = max_u f[2(i0+i)+u-3][x] + hu[u]  (clamped loads, hu masked at y-edges)
// Pass B: out[i][j] = max_u v[i][2j+u-3] + hu[u]     (x-pad cols are -inf)

#define H 256
#define W 256
#define HO 128
#define WO 128
#define TH 16               // output rows per strip
#define VPAD 4              // -inf pad columns each side of v rows
#define VSTRIDE 276         // floats per v row; bank-balanced for all b128 access patterns

__device__ __forceinline__ float4 f4max(float4 a, float4 b) {
    return make_float4(fmaxf(a.x, b.x), fmaxf(a.y, b.y), fmaxf(a.z, b.z), fmaxf(a.w, b.w));
}
__device__ __forceinline__ float4 f4adds(float4 a, float s) {
    return make_float4(a.x + s, a.y + s, a.z + s, a.w + s);
}

// vertical 7-tap max-plus for an output-row pair from 9 staged input rows
__device__ __forceinline__ void vcompute(const float4 r[9], int gy0,
                                         float h0, float h1, float h2, float NEG,
                                         float4& vA, float4& vB) {
    if (gy0 >= 0 && gy0 + 8 <= H - 1) {          // interior fast path (wave-uniform)
        vA = f4max(f4max(f4adds(f4max(r[0], r[6]), h0),
                         f4adds(f4max(r[1], r[5]), h1)),
                   f4max(f4adds(f4max(r[2], r[4]), h2), r[3]));
        vB = f4max(f4max(f4adds(f4max(r[2], r[8]), h0),
                         f4adds(f4max(r[3], r[7]), h1)),
                   f4max(f4adds(f4max(r[4], r[6]), h2), r[5]));
    } else {
        const float hu[7] = {h0, h1, h2, 0.0f, h2, h1, h0};
        float4 a = make_float4(NEG, NEG, NEG, NEG);
        float4 b = make_float4(NEG, NEG, NEG, NEG);
#pragma unroll
        for (int u = 0; u < 7; ++u) {
            const int gyA = gy0 + u;
            const int gyB = gy0 + 2 + u;
            const float hA = (gyA >= 0 && gyA < H) ? hu[u] : NEG;
            const float hB = (gyB >= 0 && gyB < H) ? hu[u] : NEG;
            a = f4max(a, f4adds(r[u], hA));
            b = f4max(b, f4adds(r[u + 2], hB));
        }
        vA = a; vB = b;
    }
}

// horizontal 7-tap max-plus from LDS + coalesced float4 store (one strip)
__device__ __forceinline__ void hpass_store(const float* __restrict__ v_, int tid,
                                            float h0, float h1, float h2,
                                            float* __restrict__ oplane, int i0) {
    const int i  = tid >> 5;                 // 0..15 (out row, strip-local)
    const int jg = tid & 31;                 // out cols 4jg..4jg+3
    const int c0 = 4 * jg;
    const float* p = &v_[i * VSTRIDE + 2 * c0];   // raw idx 8jg, f4-aligned
    const float4 a = *(const float4*)(p);
    const float4 b = *(const float4*)(p + 4);
    const float4 c = *(const float4*)(p + 8);
    const float4 d = *(const float4*)(p + 12);
    const float s[16] = {a.x, a.y, a.z, a.w, b.x, b.y, b.z, b.w,
                         c.x, c.y, c.z, c.w, d.x, d.y, d.z, d.w};
    float4 o;
    float* op = (float*)&o;
#pragma unroll
    for (int dd = 0; dd < 4; ++dd) {         // out col j=c0+dd: raw window [2dd+1, 2dd+7]
        const float m0 = fmaxf(s[2 * dd + 1], s[2 * dd + 7]) + h0;
        const float m1 = fmaxf(s[2 * dd + 2], s[2 * dd + 6]) + h1;
        const float m2 = fmaxf(s[2 * dd + 3], s[2 * dd + 5]) + h2;
        op[dd] = fmaxf(fmaxf(m0, m1), fmaxf(m2, s[2 * dd + 4]));
    }
    *(float4*)(oplane + (size_t)(i0 + i) * WO + c0) = o;
}

__global__ __launch_bounds__(512, 6)
void pp_kernel(const float* __restrict__ f, const float* __restrict__ tptr,
               float* __restrict__ out) {
    __shared__ __align__(16) float v_[TH * VSTRIDE];   // 17664 B, reused for both strips

    const int tid = threadIdx.x;
    const int bid = blockIdx.x;
    // 8192 blocks, 8 XCDs, 1024/XCD: bijective swizzle; consecutive lids on one XCD are
    // consecutive super-strips of the same plane -> cross-block y-halo hits that XCD's L2.
    const int lid   = (bid & 7) * 1024 + (bid >> 3);
    const int plane = lid >> 2;          // b*128 + c
    const int ss    = lid & 3;           // super-strip: 32 output rows
    const int i0a   = ss * 32;           // strip 0 origin
    const int i0b   = i0a + TH;          // strip 1 origin

    const float tv  = tptr[0];
    const float inv = 1.0f / (4.0f * tv);
    const float h0 = -9.0f * inv, h1 = -4.0f * inv, h2 = -1.0f * inv;  // h3 = 0
    const float NEG = -__builtin_inff();

    const float* __restrict__ fplane = f + (size_t)plane * (H * W);
    float* __restrict__ oplane = out + (size_t)plane * (HO * WO);

    // x-pad columns: v cols [-4,-1] and [256,259] = -inf. Written once (Pass A never
    // touches them; strip 1 reuses them). Covered by the first barrier.
    if (tid < 32) {
        const int r   = tid & 15;
        const int off = (tid < 16) ? 0 : (VPAD + W);
        *(float4*)(&v_[r * VSTRIDE + off]) = make_float4(NEG, NEG, NEG, NEG);
    }

    // Per-thread Pass-A item: x4 column group x output-row pair (wave-uniform pair)
    const int x4    = (tid & 63) * 4;        // float col 0..252
    const int ib    = (tid >> 6) * 2;        // tile-local rows ib, ib+1 (0..14)
    const int lofs0 = ib * VSTRIDE + VPAD + x4;

    // ---- Strip 0, Pass A: load 9 rows (clamped -> unconditional), vertical reduce ----
    const int gy0a = 2 * (i0a + ib) - 3;
    float4 r0[9];
#pragma unroll
    for (int k = 0; k < 9; ++k) {
        const int cy = min(max(gy0a + k, 0), H - 1);
        r0[k] = *(const float4*)(fplane + cy * W + x4);   // wave: contiguous 1KB, coalesced
    }
    {
        float4 vA, vB;
        vcompute(r0, gy0a, h0, h1, h2, NEG, vA, vB);
        *(float4*)(&v_[lofs0])           = vA;
        *(float4*)(&v_[lofs0 + VSTRIDE]) = vB;
    }
    __syncthreads();

    // ---- Pipeline: issue strip-1 loads BEFORE strip-0 Pass B ----
    const int gy0b = 2 * (i0b + ib) - 3;
    float4 r1[9];
#pragma unroll
    for (int k = 0; k < 9; ++k) {
        const int cy = min(max(gy0b + k, 0), H - 1);
        r1[k] = *(const float4*)(fplane + cy * W + x4);   // in flight during Pass B below
    }

    // ---- Strip 0, Pass B (LDS + VALU; overlaps r1 fetch) ----
    hpass_store(v_, tid, h0, h1, h2, oplane, i0a);
    __syncthreads();        // all strip-0 reads of v_ done before overwrite

    // ---- Strip 1, Pass A compute (vmcnt waits on r1 here) ----
    {
        float4 vA, vB;
        vcompute(r1, gy0b, h0, h1, h2, NEG, vA, vB);
        *(float4*)(&v_[lofs0])           = vA;
        *(float4*)(&v_[lofs0 + VSTRIDE]) = vB;
    }
    __syncthreads();

    // ---- Strip 1, Pass B ----
    hpass_store(v_, tid, h0, h1, h2, oplane, i0b);
}

extern "C" void kernel_launch(void* const* d_in, const int* in_sizes, int n_in,
                              void* d_out, int out_size, void* d_ws, size_t ws_size,
                              hipStream_t stream) {
    const float* f = (const float*)d_in[0];
    const float* t = (const float*)d_in[1];
    float* out = (float*)d_out;
    // 2048 planes x 4 super-strips (2 pipelined 16-row strips each), 512 threads
    pp_kernel<<<dim3(2048 * 4), dim3(512), 0, stream>>>(f, t, out);
}